// Round 2
// baseline (391.423 us; speedup 1.0000x reference)
//
#include <hip/hip_runtime.h>
#include <math.h>

// Problem constants
#define BT    96          // B*T = 8*12
#define NSEQ  512         // N
#define DMODEL 64         // D = K*d
#define RTOT  (BT * NSEQ) // 49152 rows

// Workspace layout (floats)
#define QOFF  0
#define KOFF  ((size_t)RTOT * DMODEL)          // 3145728
#define VOFF  ((size_t)2 * RTOT * DMODEL)
#define OOFF  ((size_t)3 * RTOT * DMODEL)      // attention output

#if __has_builtin(__builtin_amdgcn_exp2f)
#define EXP2F(x) __builtin_amdgcn_exp2f(x)
#else
#define EXP2F(x) exp2f(x)
#endif

// ---------------------------------------------------------------------------
// Kernel 1: QKV = relu([X|STE] @ W{7,8,9} + b{7,8,9})   (unchanged from R1)
// ---------------------------------------------------------------------------
__global__ __launch_bounds__(256) void qkv_kernel(
    const float* __restrict__ X, const float* __restrict__ STE,
    const float* __restrict__ W7, const float* __restrict__ b7,
    const float* __restrict__ W8, const float* __restrict__ b8,
    const float* __restrict__ W9, const float* __restrict__ b9,
    float* __restrict__ qkv)
{
    __shared__ float As[128][36];
    __shared__ float Ws[32][68];

    const int tid  = threadIdx.x;
    const int tx   = tid & 15;
    const int ty   = tid >> 4;
    const int rt   = blockIdx.x;
    const int wsel = blockIdx.y;

    const float* Wm = (wsel == 0) ? W7 : (wsel == 1) ? W8 : W9;
    const float* bv = (wsel == 0) ? b7 : (wsel == 1) ? b8 : b9;

    float acc[8][4];
    #pragma unroll
    for (int i = 0; i < 8; ++i)
        #pragma unroll
        for (int j = 0; j < 4; ++j) acc[i][j] = 0.f;

    const size_t rowbase = (size_t)rt * 128;

    for (int kc = 0; kc < 4; ++kc) {
        const float* src = (kc < 2) ? X : STE;
        const int koff = (kc & 1) * 32;

        __syncthreads();
        #pragma unroll
        for (int j = 0; j < 4; ++j) {
            int idx = tid + 256 * j;
            int r   = idx >> 3;
            int kq  = (idx & 7) * 4;
            float4 v = *(const float4*)(src + (rowbase + (size_t)r) * 64 + koff + kq);
            *(float4*)&As[r][kq] = v;
        }
        #pragma unroll
        for (int j = 0; j < 2; ++j) {
            int idx = tid + 256 * j;
            int kk  = idx >> 4;
            int cq  = (idx & 15) * 4;
            float4 v = *(const float4*)(Wm + (size_t)(kc * 32 + kk) * 64 + cq);
            *(float4*)&Ws[kk][cq] = v;
        }
        __syncthreads();

        #pragma unroll
        for (int k0 = 0; k0 < 32; k0 += 4) {
            float4 a[8], w[4];
            #pragma unroll
            for (int i = 0; i < 8; ++i) a[i] = *(const float4*)&As[ty * 8 + i][k0];
            #pragma unroll
            for (int j = 0; j < 4; ++j) w[j] = *(const float4*)&Ws[k0 + j][tx * 4];
            #pragma unroll
            for (int i = 0; i < 8; ++i) {
                acc[i][0] += a[i].x * w[0].x + a[i].y * w[1].x + a[i].z * w[2].x + a[i].w * w[3].x;
                acc[i][1] += a[i].x * w[0].y + a[i].y * w[1].y + a[i].z * w[2].y + a[i].w * w[3].y;
                acc[i][2] += a[i].x * w[0].z + a[i].y * w[1].z + a[i].z * w[2].z + a[i].w * w[3].z;
                acc[i][3] += a[i].x * w[0].w + a[i].y * w[1].w + a[i].z * w[2].w + a[i].w * w[3].w;
            }
        }
    }

    float* obase = qkv + (size_t)wsel * ((size_t)RTOT * DMODEL) + rowbase * 64;
    const float4 bb = *(const float4*)(bv + tx * 4);
    #pragma unroll
    for (int i = 0; i < 8; ++i) {
        float4 o;
        o.x = fmaxf(acc[i][0] + bb.x, 0.f);
        o.y = fmaxf(acc[i][1] + bb.y, 0.f);
        o.z = fmaxf(acc[i][2] + bb.z, 0.f);
        o.w = fmaxf(acc[i][3] + bb.w, 0.f);
        *(float4*)(obase + (size_t)(ty * 8 + i) * 64 + tx * 4) = o;
    }
}

// ---------------------------------------------------------------------------
// Kernel 2: per (bt, head) attention. R2 restructure:
//  - block 128 threads (2 waves), 4 q-rows per thread -> halves LDS
//    read traffic per row-key (the R1 co-bottleneck).
//  - q loaded global->registers (qs dropped from LDS): LDS 48KB -> 32KB.
//  - output written straight from registers (no LDS staging).
//  - raw v_exp_f32 (scores >= 0 since q,k relu'd: no denormal range).
// ---------------------------------------------------------------------------
__global__ __launch_bounds__(128) void attn_kernel(
    const float* __restrict__ qkv, float* __restrict__ obuf)
{
    __shared__ float ks[NSEQ][8];
    __shared__ float vs[NSEQ][8];

    const int tid = threadIdx.x;
    const int h   = blockIdx.x & 7;
    const int bt  = blockIdx.x >> 3;

    const float* Qp = qkv + QOFF;
    const float* Kp = qkv + KOFF;
    const float* Vp = qkv + VOFF;
    const size_t rowbase = (size_t)bt * NSEQ * 64 + (size_t)h * 8;

    // Stage k,v head slices: 2048 float4 total, 16 per thread.
    #pragma unroll
    for (int j = 0; j < 8; ++j) {
        int idx  = tid + 128 * j;
        int n    = idx >> 1;
        int half = (idx & 1) * 4;
        size_t g = rowbase + (size_t)n * 64 + half;
        *(float4*)&ks[n][half] = *(const float4*)(Kp + g);
        *(float4*)&vs[n][half] = *(const float4*)(Vp + g);
    }

    // 4 q-rows per thread, scaled by log2(e)/sqrt(8) at load.
    const float C = 0.51012091684045906f;
    const int n0 = tid * 4;
    float q[4][8];
    #pragma unroll
    for (int r = 0; r < 4; ++r) {
        const float* qp = Qp + rowbase + (size_t)(n0 + r) * 64;
        float4 qa = *(const float4*)(qp);
        float4 qb = *(const float4*)(qp + 4);
        q[r][0] = qa.x * C; q[r][1] = qa.y * C; q[r][2] = qa.z * C; q[r][3] = qa.w * C;
        q[r][4] = qb.x * C; q[r][5] = qb.y * C; q[r][6] = qb.z * C; q[r][7] = qb.w * C;
    }

    __syncthreads();

    float acc[4][8];
    float dsum[4];
    #pragma unroll
    for (int r = 0; r < 4; ++r) {
        dsum[r] = 0.f;
        #pragma unroll
        for (int j = 0; j < 8; ++j) acc[r][j] = 0.f;
    }

    #pragma unroll 4
    for (int m = 0; m < NSEQ; ++m) {
        const float4 ka = *(const float4*)&ks[m][0];
        const float4 kb = *(const float4*)&ks[m][4];
        float p[4];
        #pragma unroll
        for (int r = 0; r < 4; ++r) {
            float s = q[r][0] * ka.x + q[r][1] * ka.y + q[r][2] * ka.z + q[r][3] * ka.w
                    + q[r][4] * kb.x + q[r][5] * kb.y + q[r][6] * kb.z + q[r][7] * kb.w;
            p[r] = EXP2F(s);
        }
        const float4 va = *(const float4*)&vs[m][0];
        const float4 vb = *(const float4*)&vs[m][4];
        #pragma unroll
        for (int r = 0; r < 4; ++r) {
            dsum[r] += p[r];
            acc[r][0] += p[r] * va.x; acc[r][1] += p[r] * va.y;
            acc[r][2] += p[r] * va.z; acc[r][3] += p[r] * va.w;
            acc[r][4] += p[r] * vb.x; acc[r][5] += p[r] * vb.y;
            acc[r][6] += p[r] * vb.z; acc[r][7] += p[r] * vb.w;
        }
    }

    #pragma unroll
    for (int r = 0; r < 4; ++r) {
        const float inv = 1.f / dsum[r];
        float4 oa, ob;
        oa.x = acc[r][0] * inv; oa.y = acc[r][1] * inv;
        oa.z = acc[r][2] * inv; oa.w = acc[r][3] * inv;
        ob.x = acc[r][4] * inv; ob.y = acc[r][5] * inv;
        ob.z = acc[r][6] * inv; ob.w = acc[r][7] * inv;
        float* op = obuf + rowbase + (size_t)(n0 + r) * 64;
        *(float4*)(op)     = oa;
        *(float4*)(op + 4) = ob;
    }
}

// ---------------------------------------------------------------------------
// Kernel 3: out = relu(O @ W10 + b10) @ W11 + b11   (unchanged from R1)
// ---------------------------------------------------------------------------
__global__ __launch_bounds__(256) void proj_kernel(
    const float* __restrict__ obuf,
    const float* __restrict__ W10, const float* __restrict__ b10,
    const float* __restrict__ W11, const float* __restrict__ b11,
    float* __restrict__ out)
{
    __shared__ float Os[64][68];
    __shared__ float Ts[64][68];
    __shared__ float Was[64][68];
    __shared__ float Wbs[64][68];

    const int tid = threadIdx.x;
    const int tx  = tid & 15;
    const int ty  = tid >> 4;
    const size_t r0 = (size_t)blockIdx.x * 64;

    #pragma unroll
    for (int j = 0; j < 4; ++j) {
        int idx = tid + 256 * j;
        int r   = idx >> 4;
        int cq  = (idx & 15) * 4;
        *(float4*)&Os[r][cq]  = *(const float4*)(obuf + (r0 + (size_t)r) * 64 + cq);
        *(float4*)&Was[r][cq] = *(const float4*)(W10 + (size_t)r * 64 + cq);
        *(float4*)&Wbs[r][cq] = *(const float4*)(W11 + (size_t)r * 64 + cq);
    }
    __syncthreads();

    float acc[4][4];
    #pragma unroll
    for (int i = 0; i < 4; ++i)
        #pragma unroll
        for (int j = 0; j < 4; ++j) acc[i][j] = 0.f;

    #pragma unroll
    for (int k0 = 0; k0 < 64; k0 += 4) {
        float4 a[4], w[4];
        #pragma unroll
        for (int i = 0; i < 4; ++i) a[i] = *(const float4*)&Os[ty * 4 + i][k0];
        #pragma unroll
        for (int j = 0; j < 4; ++j) w[j] = *(const float4*)&Was[k0 + j][tx * 4];
        #pragma unroll
        for (int i = 0; i < 4; ++i) {
            acc[i][0] += a[i].x * w[0].x + a[i].y * w[1].x + a[i].z * w[2].x + a[i].w * w[3].x;
            acc[i][1] += a[i].x * w[0].y + a[i].y * w[1].y + a[i].z * w[2].y + a[i].w * w[3].y;
            acc[i][2] += a[i].x * w[0].z + a[i].y * w[1].z + a[i].z * w[2].z + a[i].w * w[3].z;
            acc[i][3] += a[i].x * w[0].w + a[i].y * w[1].w + a[i].z * w[2].w + a[i].w * w[3].w;
        }
    }

    const float4 ba = *(const float4*)(b10 + tx * 4);
    #pragma unroll
    for (int i = 0; i < 4; ++i) {
        float4 t;
        t.x = fmaxf(acc[i][0] + ba.x, 0.f);
        t.y = fmaxf(acc[i][1] + ba.y, 0.f);
        t.z = fmaxf(acc[i][2] + ba.z, 0.f);
        t.w = fmaxf(acc[i][3] + ba.w, 0.f);
        *(float4*)&Ts[ty * 4 + i][tx * 4] = t;
    }
    __syncthreads();

    #pragma unroll
    for (int i = 0; i < 4; ++i)
        #pragma unroll
        for (int j = 0; j < 4; ++j) acc[i][j] = 0.f;

    #pragma unroll
    for (int k0 = 0; k0 < 64; k0 += 4) {
        float4 a[4], w[4];
        #pragma unroll
        for (int i = 0; i < 4; ++i) a[i] = *(const float4*)&Ts[ty * 4 + i][k0];
        #pragma unroll
        for (int j = 0; j < 4; ++j) w[j] = *(const float4*)&Wbs[k0 + j][tx * 4];
        #pragma unroll
        for (int i = 0; i < 4; ++i) {
            acc[i][0] += a[i].x * w[0].x + a[i].y * w[1].x + a[i].z * w[2].x + a[i].w * w[3].x;
            acc[i][1] += a[i].x * w[0].y + a[i].y * w[1].y + a[i].z * w[2].y + a[i].w * w[3].y;
            acc[i][2] += a[i].x * w[0].z + a[i].y * w[1].z + a[i].z * w[2].z + a[i].w * w[3].z;
            acc[i][3] += a[i].x * w[0].w + a[i].y * w[1].w + a[i].z * w[2].w + a[i].w * w[3].w;
        }
    }

    const float4 bb = *(const float4*)(b11 + tx * 4);
    #pragma unroll
    for (int i = 0; i < 4; ++i) {
        float4 o;
        o.x = acc[i][0] + bb.x;
        o.y = acc[i][1] + bb.y;
        o.z = acc[i][2] + bb.z;
        o.w = acc[i][3] + bb.w;
        *(float4*)(out + (r0 + (size_t)(ty * 4 + i)) * 64 + tx * 4) = o;
    }
}

// ---------------------------------------------------------------------------
extern "C" void kernel_launch(void* const* d_in, const int* in_sizes, int n_in,
                              void* d_out, int out_size, void* d_ws, size_t ws_size,
                              hipStream_t stream)
{
    const float* X   = (const float*)d_in[0];
    const float* STE = (const float*)d_in[1];
    const float* W7  = (const float*)d_in[2];
    const float* b7  = (const float*)d_in[3];
    const float* W8  = (const float*)d_in[4];
    const float* b8  = (const float*)d_in[5];
    const float* W9  = (const float*)d_in[6];
    const float* b9  = (const float*)d_in[7];
    const float* W10 = (const float*)d_in[8];
    const float* b10 = (const float*)d_in[9];
    const float* W11 = (const float*)d_in[10];
    const float* b11 = (const float*)d_in[11];

    float* ws  = (float*)d_ws;   // Q | K | V | O
    float* out = (float*)d_out;

    qkv_kernel<<<dim3(RTOT / 128, 3), 256, 0, stream>>>(X, STE, W7, b7, W8, b8, W9, b9, ws);
    attn_kernel<<<dim3(BT * 8), 128, 0, stream>>>(ws, ws + OOFF);
    proj_kernel<<<dim3(RTOT / 64), 256, 0, stream>>>(ws + OOFF, W10, b10, W11, b11, out);
}

// Round 3
// 310.722 us; speedup vs baseline: 1.2597x; 1.2597x over previous
//
#include <hip/hip_runtime.h>
#include <math.h>

// Problem constants
#define BT    96          // B*T = 8*12
#define NSEQ  512         // N
#define DMODEL 64         // D = K*d
#define RTOT  (BT * NSEQ) // 49152 rows

// Workspace layout (floats)
#define QOFF  0
#define KOFF  ((size_t)RTOT * DMODEL)          // 3145728
#define VOFF  ((size_t)2 * RTOT * DMODEL)
#define OOFF  ((size_t)3 * RTOT * DMODEL)      // attention output

#if __has_builtin(__builtin_amdgcn_exp2f)
#define EXP2F(x) __builtin_amdgcn_exp2f(x)
#else
#define EXP2F(x) exp2f(x)
#endif

// ---------------------------------------------------------------------------
// Kernel 1: QKV = relu([X|STE] @ W{7,8,9} + b{7,8,9})   (unchanged from R1)
// ---------------------------------------------------------------------------
__global__ __launch_bounds__(256) void qkv_kernel(
    const float* __restrict__ X, const float* __restrict__ STE,
    const float* __restrict__ W7, const float* __restrict__ b7,
    const float* __restrict__ W8, const float* __restrict__ b8,
    const float* __restrict__ W9, const float* __restrict__ b9,
    float* __restrict__ qkv)
{
    __shared__ float As[128][36];
    __shared__ float Ws[32][68];

    const int tid  = threadIdx.x;
    const int tx   = tid & 15;
    const int ty   = tid >> 4;
    const int rt   = blockIdx.x;
    const int wsel = blockIdx.y;

    const float* Wm = (wsel == 0) ? W7 : (wsel == 1) ? W8 : W9;
    const float* bv = (wsel == 0) ? b7 : (wsel == 1) ? b8 : b9;

    float acc[8][4];
    #pragma unroll
    for (int i = 0; i < 8; ++i)
        #pragma unroll
        for (int j = 0; j < 4; ++j) acc[i][j] = 0.f;

    const size_t rowbase = (size_t)rt * 128;

    for (int kc = 0; kc < 4; ++kc) {
        const float* src = (kc < 2) ? X : STE;
        const int koff = (kc & 1) * 32;

        __syncthreads();
        #pragma unroll
        for (int j = 0; j < 4; ++j) {
            int idx = tid + 256 * j;
            int r   = idx >> 3;
            int kq  = (idx & 7) * 4;
            float4 v = *(const float4*)(src + (rowbase + (size_t)r) * 64 + koff + kq);
            *(float4*)&As[r][kq] = v;
        }
        #pragma unroll
        for (int j = 0; j < 2; ++j) {
            int idx = tid + 256 * j;
            int kk  = idx >> 4;
            int cq  = (idx & 15) * 4;
            float4 v = *(const float4*)(Wm + (size_t)(kc * 32 + kk) * 64 + cq);
            *(float4*)&Ws[kk][cq] = v;
        }
        __syncthreads();

        #pragma unroll
        for (int k0 = 0; k0 < 32; k0 += 4) {
            float4 a[8], w[4];
            #pragma unroll
            for (int i = 0; i < 8; ++i) a[i] = *(const float4*)&As[ty * 8 + i][k0];
            #pragma unroll
            for (int j = 0; j < 4; ++j) w[j] = *(const float4*)&Ws[k0 + j][tx * 4];
            #pragma unroll
            for (int i = 0; i < 8; ++i) {
                acc[i][0] += a[i].x * w[0].x + a[i].y * w[1].x + a[i].z * w[2].x + a[i].w * w[3].x;
                acc[i][1] += a[i].x * w[0].y + a[i].y * w[1].y + a[i].z * w[2].y + a[i].w * w[3].y;
                acc[i][2] += a[i].x * w[0].z + a[i].y * w[1].z + a[i].z * w[2].z + a[i].w * w[3].z;
                acc[i][3] += a[i].x * w[0].w + a[i].y * w[1].w + a[i].z * w[2].w + a[i].w * w[3].w;
            }
        }
    }

    float* obase = qkv + (size_t)wsel * ((size_t)RTOT * DMODEL) + rowbase * 64;
    const float4 bb = *(const float4*)(bv + tx * 4);
    #pragma unroll
    for (int i = 0; i < 8; ++i) {
        float4 o;
        o.x = fmaxf(acc[i][0] + bb.x, 0.f);
        o.y = fmaxf(acc[i][1] + bb.y, 0.f);
        o.z = fmaxf(acc[i][2] + bb.z, 0.f);
        o.w = fmaxf(acc[i][3] + bb.w, 0.f);
        *(float4*)(obase + (size_t)(ty * 8 + i) * 64 + tx * 4) = o;
    }
}

// ---------------------------------------------------------------------------
// Kernel 2 (R3): attention with NO LDS.
//  - k/v rows are wave-uniform (address depends only on blockIdx + loop idx):
//    read straight from global so the compiler scalarizes to s_load
//    (all ptrs __restrict__ -> noclobber); k/v live in SGPRs, FMAs are
//    v_fmac(sgpr, vgpr). Worst case: same-address VMEM broadcast via L1/L2.
//  - 1 q-row/thread, grid 96*8*2 = 1536 blocks x 256 thr -> 24 waves/CU:
//    latency actually hidden (R2 failed at 6 waves/CU).
//  - LDS 0 bytes -> occupancy not LDS-capped.
// ---------------------------------------------------------------------------
__global__ __launch_bounds__(256) void attn_kernel(
    const float* __restrict__ qkv, float* __restrict__ obuf)
{
    const int tid = threadIdx.x;
    const int qt  = blockIdx.x & 1;
    const int h   = (blockIdx.x >> 1) & 7;
    const int bt  = blockIdx.x >> 4;

    const size_t rowbase = (size_t)bt * NSEQ * 64 + (size_t)h * 8;
    const float* Kb = qkv + KOFF + rowbase;   // row m at Kb + m*64
    const float* Vb = qkv + VOFF + rowbase;

    // One q-row per thread, scaled by log2(e)/sqrt(8) at load.
    const float C = 0.51012091684045906f;
    const int n = qt * 256 + tid;
    const float* qp = qkv + QOFF + rowbase + (size_t)n * 64;
    float4 qa = *(const float4*)(qp);
    float4 qb = *(const float4*)(qp + 4);
    float q[8];
    q[0] = qa.x * C; q[1] = qa.y * C; q[2] = qa.z * C; q[3] = qa.w * C;
    q[4] = qb.x * C; q[5] = qb.y * C; q[6] = qb.z * C; q[7] = qb.w * C;

    float acc[8];
    #pragma unroll
    for (int j = 0; j < 8; ++j) acc[j] = 0.f;
    float dsum = 0.f;

    #pragma unroll 4
    for (int m = 0; m < NSEQ; ++m) {
        const float* kr = Kb + (size_t)m * 64;   // wave-uniform address
        const float ka0 = kr[0], ka1 = kr[1], ka2 = kr[2], ka3 = kr[3];
        const float ka4 = kr[4], ka5 = kr[5], ka6 = kr[6], ka7 = kr[7];
        float s = q[0] * ka0 + q[1] * ka1 + q[2] * ka2 + q[3] * ka3
                + q[4] * ka4 + q[5] * ka5 + q[6] * ka6 + q[7] * ka7;
        float p = EXP2F(s);
        const float* vr = Vb + (size_t)m * 64;   // wave-uniform address
        const float va0 = vr[0], va1 = vr[1], va2 = vr[2], va3 = vr[3];
        const float va4 = vr[4], va5 = vr[5], va6 = vr[6], va7 = vr[7];
        dsum += p;
        acc[0] += p * va0; acc[1] += p * va1; acc[2] += p * va2; acc[3] += p * va3;
        acc[4] += p * va4; acc[5] += p * va5; acc[6] += p * va6; acc[7] += p * va7;
    }

    const float inv = 1.f / dsum;
    float4 oa, ob;
    oa.x = acc[0] * inv; oa.y = acc[1] * inv; oa.z = acc[2] * inv; oa.w = acc[3] * inv;
    ob.x = acc[4] * inv; ob.y = acc[5] * inv; ob.z = acc[6] * inv; ob.w = acc[7] * inv;
    float* op = obuf + rowbase + (size_t)n * 64;
    *(float4*)(op)     = oa;
    *(float4*)(op + 4) = ob;
}

// ---------------------------------------------------------------------------
// Kernel 3: out = relu(O @ W10 + b10) @ W11 + b11   (unchanged from R1)
// ---------------------------------------------------------------------------
__global__ __launch_bounds__(256) void proj_kernel(
    const float* __restrict__ obuf,
    const float* __restrict__ W10, const float* __restrict__ b10,
    const float* __restrict__ W11, const float* __restrict__ b11,
    float* __restrict__ out)
{
    __shared__ float Os[64][68];
    __shared__ float Ts[64][68];
    __shared__ float Was[64][68];
    __shared__ float Wbs[64][68];

    const int tid = threadIdx.x;
    const int tx  = tid & 15;
    const int ty  = tid >> 4;
    const size_t r0 = (size_t)blockIdx.x * 64;

    #pragma unroll
    for (int j = 0; j < 4; ++j) {
        int idx = tid + 256 * j;
        int r   = idx >> 4;
        int cq  = (idx & 15) * 4;
        *(float4*)&Os[r][cq]  = *(const float4*)(obuf + (r0 + (size_t)r) * 64 + cq);
        *(float4*)&Was[r][cq] = *(const float4*)(W10 + (size_t)r * 64 + cq);
        *(float4*)&Wbs[r][cq] = *(const float4*)(W11 + (size_t)r * 64 + cq);
    }
    __syncthreads();

    float acc[4][4];
    #pragma unroll
    for (int i = 0; i < 4; ++i)
        #pragma unroll
        for (int j = 0; j < 4; ++j) acc[i][j] = 0.f;

    #pragma unroll
    for (int k0 = 0; k0 < 64; k0 += 4) {
        float4 a[4], w[4];
        #pragma unroll
        for (int i = 0; i < 4; ++i) a[i] = *(const float4*)&Os[ty * 4 + i][k0];
        #pragma unroll
        for (int j = 0; j < 4; ++j) w[j] = *(const float4*)&Was[k0 + j][tx * 4];
        #pragma unroll
        for (int i = 0; i < 4; ++i) {
            acc[i][0] += a[i].x * w[0].x + a[i].y * w[1].x + a[i].z * w[2].x + a[i].w * w[3].x;
            acc[i][1] += a[i].x * w[0].y + a[i].y * w[1].y + a[i].z * w[2].y + a[i].w * w[3].y;
            acc[i][2] += a[i].x * w[0].z + a[i].y * w[1].z + a[i].z * w[2].z + a[i].w * w[3].z;
            acc[i][3] += a[i].x * w[0].w + a[i].y * w[1].w + a[i].z * w[2].w + a[i].w * w[3].w;
        }
    }

    const float4 ba = *(const float4*)(b10 + tx * 4);
    #pragma unroll
    for (int i = 0; i < 4; ++i) {
        float4 t;
        t.x = fmaxf(acc[i][0] + ba.x, 0.f);
        t.y = fmaxf(acc[i][1] + ba.y, 0.f);
        t.z = fmaxf(acc[i][2] + ba.z, 0.f);
        t.w = fmaxf(acc[i][3] + ba.w, 0.f);
        *(float4*)&Ts[ty * 4 + i][tx * 4] = t;
    }
    __syncthreads();

    #pragma unroll
    for (int i = 0; i < 4; ++i)
        #pragma unroll
        for (int j = 0; j < 4; ++j) acc[i][j] = 0.f;

    #pragma unroll
    for (int k0 = 0; k0 < 64; k0 += 4) {
        float4 a[4], w[4];
        #pragma unroll
        for (int i = 0; i < 4; ++i) a[i] = *(const float4*)&Ts[ty * 4 + i][k0];
        #pragma unroll
        for (int j = 0; j < 4; ++j) w[j] = *(const float4*)&Wbs[k0 + j][tx * 4];
        #pragma unroll
        for (int i = 0; i < 4; ++i) {
            acc[i][0] += a[i].x * w[0].x + a[i].y * w[1].x + a[i].z * w[2].x + a[i].w * w[3].x;
            acc[i][1] += a[i].x * w[0].y + a[i].y * w[1].y + a[i].z * w[2].y + a[i].w * w[3].y;
            acc[i][2] += a[i].x * w[0].z + a[i].y * w[1].z + a[i].z * w[2].z + a[i].w * w[3].z;
            acc[i][3] += a[i].x * w[0].w + a[i].y * w[1].w + a[i].z * w[2].w + a[i].w * w[3].w;
        }
    }

    const float4 bb = *(const float4*)(b11 + tx * 4);
    #pragma unroll
    for (int i = 0; i < 4; ++i) {
        float4 o;
        o.x = acc[i][0] + bb.x;
        o.y = acc[i][1] + bb.y;
        o.z = acc[i][2] + bb.z;
        o.w = acc[i][3] + bb.w;
        *(float4*)(out + (r0 + (size_t)(ty * 4 + i)) * 64 + tx * 4) = o;
    }
}

// ---------------------------------------------------------------------------
extern "C" void kernel_launch(void* const* d_in, const int* in_sizes, int n_in,
                              void* d_out, int out_size, void* d_ws, size_t ws_size,
                              hipStream_t stream)
{
    const float* X   = (const float*)d_in[0];
    const float* STE = (const float*)d_in[1];
    const float* W7  = (const float*)d_in[2];
    const float* b7  = (const float*)d_in[3];
    const float* W8  = (const float*)d_in[4];
    const float* b8  = (const float*)d_in[5];
    const float* W9  = (const float*)d_in[6];
    const float* b9  = (const float*)d_in[7];
    const float* W10 = (const float*)d_in[8];
    const float* b10 = (const float*)d_in[9];
    const float* W11 = (const float*)d_in[10];
    const float* b11 = (const float*)d_in[11];

    float* ws  = (float*)d_ws;   // Q | K | V | O
    float* out = (float*)d_out;

    qkv_kernel<<<dim3(RTOT / 128, 3), 256, 0, stream>>>(X, STE, W7, b7, W8, b8, W9, b9, ws);
    attn_kernel<<<dim3(BT * 8 * 2), 256, 0, stream>>>(ws, ws + OOFF);
    proj_kernel<<<dim3(RTOT / 64), 256, 0, stream>>>(ws + OOFF, W10, b10, W11, b11, out);
}

// Round 4
// 237.677 us; speedup vs baseline: 1.6469x; 1.3073x over previous
//
#include <hip/hip_runtime.h>
#include <math.h>

// Problem constants
#define BT    96          // B*T = 8*12
#define NSEQ  512         // N
#define DMODEL 64         // D = K*d
#define RTOT  (BT * NSEQ) // 49152 rows

// Workspace layout (floats)
#define QOFF  0
#define KOFF  ((size_t)RTOT * DMODEL)
#define VOFF  ((size_t)2 * RTOT * DMODEL)
#define OOFF  ((size_t)3 * RTOT * DMODEL)

#if __has_builtin(__builtin_amdgcn_exp2f)
#define EXP2F(x) __builtin_amdgcn_exp2f(x)
#else
#define EXP2F(x) exp2f(x)
#endif

typedef __attribute__((ext_vector_type(8)))  short short8;
typedef __attribute__((ext_vector_type(16))) float float16v;

static __device__ inline short8 as_s8(uint4 u) {
    union { uint4 u; short8 s; } x; x.u = u; return x.s;
}

// Split 8 non-negative fp32 into packed bf16 hi (truncate) and bf16 lo
// (exact residual, then truncate). Pair (2t,2t+1) -> dword: lo16=elem 2t.
static __device__ inline void split_pack8(const float* v, uint4* hi, uint4* lo) {
    uint32_t h[4], l[4];
    #pragma unroll
    for (int t = 0; t < 4; ++t) {
        float x0 = v[2 * t], x1 = v[2 * t + 1];
        uint32_t u0 = __float_as_uint(x0), u1 = __float_as_uint(x1);
        uint32_t h0 = u0 & 0xffff0000u, h1 = u1 & 0xffff0000u;
        h[t] = h1 | (u0 >> 16);
        float l0 = x0 - __uint_as_float(h0);   // exact
        float l1 = x1 - __uint_as_float(h1);   // exact
        l[t] = (__float_as_uint(l1) & 0xffff0000u) | (__float_as_uint(l0) >> 16);
    }
    *hi = make_uint4(h[0], h[1], h[2], h[3]);
    *lo = make_uint4(l[0], l[1], l[2], l[3]);
}

// ---------------------------------------------------------------------------
// Kernel 1: QKV = relu([X|STE] @ W{7,8,9} + b{7,8,9})   (unchanged)
// ---------------------------------------------------------------------------
__global__ __launch_bounds__(256) void qkv_kernel(
    const float* __restrict__ X, const float* __restrict__ STE,
    const float* __restrict__ W7, const float* __restrict__ b7,
    const float* __restrict__ W8, const float* __restrict__ b8,
    const float* __restrict__ W9, const float* __restrict__ b9,
    float* __restrict__ qkv)
{
    __shared__ float As[128][36];
    __shared__ float Ws[32][68];

    const int tid  = threadIdx.x;
    const int tx   = tid & 15;
    const int ty   = tid >> 4;
    const int rt   = blockIdx.x;
    const int wsel = blockIdx.y;

    const float* Wm = (wsel == 0) ? W7 : (wsel == 1) ? W8 : W9;
    const float* bv = (wsel == 0) ? b7 : (wsel == 1) ? b8 : b9;

    float acc[8][4];
    #pragma unroll
    for (int i = 0; i < 8; ++i)
        #pragma unroll
        for (int j = 0; j < 4; ++j) acc[i][j] = 0.f;

    const size_t rowbase = (size_t)rt * 128;

    for (int kc = 0; kc < 4; ++kc) {
        const float* src = (kc < 2) ? X : STE;
        const int koff = (kc & 1) * 32;

        __syncthreads();
        #pragma unroll
        for (int j = 0; j < 4; ++j) {
            int idx = tid + 256 * j;
            int r   = idx >> 3;
            int kq  = (idx & 7) * 4;
            float4 v = *(const float4*)(src + (rowbase + (size_t)r) * 64 + koff + kq);
            *(float4*)&As[r][kq] = v;
        }
        #pragma unroll
        for (int j = 0; j < 2; ++j) {
            int idx = tid + 256 * j;
            int kk  = idx >> 4;
            int cq  = (idx & 15) * 4;
            float4 v = *(const float4*)(Wm + (size_t)(kc * 32 + kk) * 64 + cq);
            *(float4*)&Ws[kk][cq] = v;
        }
        __syncthreads();

        #pragma unroll
        for (int k0 = 0; k0 < 32; k0 += 4) {
            float4 a[8], w[4];
            #pragma unroll
            for (int i = 0; i < 8; ++i) a[i] = *(const float4*)&As[ty * 8 + i][k0];
            #pragma unroll
            for (int j = 0; j < 4; ++j) w[j] = *(const float4*)&Ws[k0 + j][tx * 4];
            #pragma unroll
            for (int i = 0; i < 8; ++i) {
                acc[i][0] += a[i].x * w[0].x + a[i].y * w[1].x + a[i].z * w[2].x + a[i].w * w[3].x;
                acc[i][1] += a[i].x * w[0].y + a[i].y * w[1].y + a[i].z * w[2].y + a[i].w * w[3].y;
                acc[i][2] += a[i].x * w[0].z + a[i].y * w[1].z + a[i].z * w[2].z + a[i].w * w[3].z;
                acc[i][3] += a[i].x * w[0].w + a[i].y * w[1].w + a[i].z * w[2].w + a[i].w * w[3].w;
            }
        }
    }

    float* obase = qkv + (size_t)wsel * ((size_t)RTOT * DMODEL) + rowbase * 64;
    const float4 bb = *(const float4*)(bv + tx * 4);
    #pragma unroll
    for (int i = 0; i < 8; ++i) {
        float4 o;
        o.x = fmaxf(acc[i][0] + bb.x, 0.f);
        o.y = fmaxf(acc[i][1] + bb.y, 0.f);
        o.z = fmaxf(acc[i][2] + bb.z, 0.f);
        o.w = fmaxf(acc[i][3] + bb.w, 0.f);
        *(float4*)(obase + (size_t)(ty * 8 + i) * 64 + tx * 4) = o;
    }
}

// ---------------------------------------------------------------------------
// Kernel 2 (R4): MFMA attention, one block per (bt, head), 256 threads.
//
// S^T-tile = mfma(A=K-rows, B=Q-rows) so the S C-frag's lane index (col) is
// the QUERY -- exactly the lane index the PV A-operand wants. The C-reg ->
// K-slot key permutation sigma = [0,1,2,3,8..11 | 4..7,12..15] (per half h)
// is absorbed into the V B-frags staged in LDS. Split-bf16 (hi+lo, exact for
// non-negative relu'd values) gives ~fp32 precision:
//   S = mfma([k_hi|k_hi],[q_hi|q_lo]) + mfma([k_lo|0],[q_hi|q_hi])
//   O = sum over 16-key steps of  p_hi*v_hi + p_lo*v_hi + p_hi*v_lo
// V carries a ones-column (dim 8) so the softmax denominator accumulates in
// the same C-frag (no-max softmax is safe: s>=0 => p>=1 => denom>=512).
// ---------------------------------------------------------------------------
__global__ __launch_bounds__(256) void attn_kernel(
    const float* __restrict__ qkv, float* __restrict__ obuf)
{
    __shared__ uint4 ak1[16 * 32];        // k_hi frags  (8 KB)
    __shared__ uint4 ak2[16 * 32];        // k_lo frags  (8 KB)
    __shared__ uint4 vfh[32 * 2 * 9];     // V_hi B-frag entries (9 KB)
    __shared__ uint4 vfl[32 * 2 * 9];     // V_lo B-frag entries (9 KB)
    __shared__ uint4 zslab;               // zero entry

    const int tid  = threadIdx.x;
    const int lane = tid & 63;
    const int l31  = lane & 31;
    const int hh   = lane >> 5;           // half of wave: k-slot group
    const int wv   = tid >> 6;            // wave id 0..3
    const int head = blockIdx.x & 7;
    const int bt   = blockIdx.x >> 3;

    const size_t rowbase = (size_t)bt * NSEQ * 64 + (size_t)head * 8;
    const float* Qp = qkv + QOFF + rowbase;
    const float* Kp = qkv + KOFF + rowbase;
    const float* Vp = qkv + VOFF + rowbase;

    if (tid == 0) zslab = make_uint4(0, 0, 0, 0);

    // ---- Stage K fragments: ak1[k]=hi, ak2[k]=lo (dims 0..7 packed) ----
    for (int k = tid; k < NSEQ; k += 256) {
        const float* kr = Kp + (size_t)k * 64;
        float kv[8];
        float4 a = *(const float4*)(kr);
        float4 b = *(const float4*)(kr + 4);
        kv[0] = a.x; kv[1] = a.y; kv[2] = a.z; kv[3] = a.w;
        kv[4] = b.x; kv[5] = b.y; kv[6] = b.z; kv[7] = b.w;
        uint4 hi, lo;
        split_pack8(kv, &hi, &lo);
        ak1[k] = hi;
        ak2[k] = lo;
    }

    // ---- Stage V B-frag entries with the sigma key permutation ----
    // entry e = (s, hv, n): s=K-step (16 keys), hv=slot-half, n=dim (8=ones)
    for (int e = tid; e < 32 * 2 * 9; e += 256) {
        int s  = e / 18;
        int r  = e % 18;
        int hv = r / 9;
        int n  = r % 9;
        float vv[8];
        #pragma unroll
        for (int j = 0; j < 8; ++j) {
            int key = 16 * s + ((j < 4) ? (4 * hv + j) : (8 + 4 * hv + (j - 4)));
            vv[j] = (n < 8) ? Vp[(size_t)key * 64 + n] : 1.0f;
        }
        uint4 hi, lo;
        split_pack8(vv, &hi, &lo);   // for n==8: hi=bf16(1.0) pairs, lo=0
        vfh[e] = hi;
        vfl[e] = lo;
    }

    __syncthreads();

    const float C = 0.51012091684045906f;  // log2(e)/sqrt(8), folded into q

    // ---- 4 query-tiles of 32 per wave ----
    for (int qt = wv; qt < 16; qt += 4) {
        // Build Q B-frags: bq1 = [q_hi | q_lo], bq2 = [q_hi | q_hi]
        const float* qp = Qp + (size_t)(qt * 32 + l31) * 64;
        float qv[8];
        {
            float4 a = *(const float4*)(qp);
            float4 b = *(const float4*)(qp + 4);
            qv[0] = a.x * C; qv[1] = a.y * C; qv[2] = a.z * C; qv[3] = a.w * C;
            qv[4] = b.x * C; qv[5] = b.y * C; qv[6] = b.z * C; qv[7] = b.w * C;
        }
        uint4 qhi, qlo;
        split_pack8(qv, &qhi, &qlo);
        const uint4 bq1 = hh ? qlo : qhi;
        const uint4 bq2 = qhi;

        float16v O;
        #pragma unroll
        for (int i = 0; i < 16; ++i) O[i] = 0.f;

        for (int c = 0; c < 16; ++c) {
            const uint4 a1 = ak1[c * 32 + l31];
            const uint4 a2 = hh ? zslab : ak2[c * 32 + l31];
            const int s0 = 2 * c, s1 = 2 * c + 1;
            const int vi0 = (s0 * 2 + hh) * 9;
            const int vi1 = (s1 * 2 + hh) * 9;
            const bool act = (l31 < 9);
            const uint4 bh0 = act ? vfh[vi0 + l31] : zslab;
            const uint4 bl0 = act ? vfl[vi0 + l31] : zslab;
            const uint4 bh1 = act ? vfh[vi1 + l31] : zslab;
            const uint4 bl1 = act ? vfl[vi1 + l31] : zslab;

            float16v S;
            #pragma unroll
            for (int i = 0; i < 16; ++i) S[i] = 0.f;
            S = __builtin_amdgcn_mfma_f32_32x32x16_bf16(as_s8(a1), as_s8(bq1), S, 0, 0, 0);
            S = __builtin_amdgcn_mfma_f32_32x32x16_bf16(as_s8(a2), as_s8(bq2), S, 0, 0, 0);

            float pv[16];
            #pragma unroll
            for (int i = 0; i < 16; ++i) pv[i] = EXP2F(S[i]);

            uint4 ph0, pl0, ph1, pl1;
            split_pack8(&pv[0], &ph0, &pl0);
            split_pack8(&pv[8], &ph1, &pl1);

            O = __builtin_amdgcn_mfma_f32_32x32x16_bf16(as_s8(ph0), as_s8(bh0), O, 0, 0, 0);
            O = __builtin_amdgcn_mfma_f32_32x32x16_bf16(as_s8(pl0), as_s8(bh0), O, 0, 0, 0);
            O = __builtin_amdgcn_mfma_f32_32x32x16_bf16(as_s8(ph0), as_s8(bl0), O, 0, 0, 0);
            O = __builtin_amdgcn_mfma_f32_32x32x16_bf16(as_s8(ph1), as_s8(bh1), O, 0, 0, 0);
            O = __builtin_amdgcn_mfma_f32_32x32x16_bf16(as_s8(pl1), as_s8(bh1), O, 0, 0, 0);
            O = __builtin_amdgcn_mfma_f32_32x32x16_bf16(as_s8(ph1), as_s8(bl1), O, 0, 0, 0);
        }

        // Epilogue: denom lives in col 8 (lane 8 / lane 40); broadcast within
        // each 32-lane half via ds_swizzle (or_mask=8).
        #pragma unroll
        for (int r = 0; r < 16; ++r) {
            float den = __uint_as_float(
                __builtin_amdgcn_ds_swizzle(__float_as_uint(O[r]), 0x100));
            float o = O[r] / den;
            if (l31 < 8) {
                int row = (r & 3) + 8 * (r >> 2) + 4 * hh;
                obuf[rowbase + (size_t)(qt * 32 + row) * 64 + l31] = o;
            }
        }
    }
}

// ---------------------------------------------------------------------------
// Kernel 3: out = relu(O @ W10 + b10) @ W11 + b11   (unchanged)
// ---------------------------------------------------------------------------
__global__ __launch_bounds__(256) void proj_kernel(
    const float* __restrict__ obuf,
    const float* __restrict__ W10, const float* __restrict__ b10,
    const float* __restrict__ W11, const float* __restrict__ b11,
    float* __restrict__ out)
{
    __shared__ float Os[64][68];
    __shared__ float Ts[64][68];
    __shared__ float Was[64][68];
    __shared__ float Wbs[64][68];

    const int tid = threadIdx.x;
    const int tx  = tid & 15;
    const int ty  = tid >> 4;
    const size_t r0 = (size_t)blockIdx.x * 64;

    #pragma unroll
    for (int j = 0; j < 4; ++j) {
        int idx = tid + 256 * j;
        int r   = idx >> 4;
        int cq  = (idx & 15) * 4;
        *(float4*)&Os[r][cq]  = *(const float4*)(obuf + (r0 + (size_t)r) * 64 + cq);
        *(float4*)&Was[r][cq] = *(const float4*)(W10 + (size_t)r * 64 + cq);
        *(float4*)&Wbs[r][cq] = *(const float4*)(W11 + (size_t)r * 64 + cq);
    }
    __syncthreads();

    float acc[4][4];
    #pragma unroll
    for (int i = 0; i < 4; ++i)
        #pragma unroll
        for (int j = 0; j < 4; ++j) acc[i][j] = 0.f;

    #pragma unroll
    for (int k0 = 0; k0 < 64; k0 += 4) {
        float4 a[4], w[4];
        #pragma unroll
        for (int i = 0; i < 4; ++i) a[i] = *(const float4*)&Os[ty * 4 + i][k0];
        #pragma unroll
        for (int j = 0; j < 4; ++j) w[j] = *(const float4*)&Was[k0 + j][tx * 4];
        #pragma unroll
        for (int i = 0; i < 4; ++i) {
            acc[i][0] += a[i].x * w[0].x + a[i].y * w[1].x + a[i].z * w[2].x + a[i].w * w[3].x;
            acc[i][1] += a[i].x * w[0].y + a[i].y * w[1].y + a[i].z * w[2].y + a[i].w * w[3].y;
            acc[i][2] += a[i].x * w[0].z + a[i].y * w[1].z + a[i].z * w[2].z + a[i].w * w[3].z;
            acc[i][3] += a[i].x * w[0].w + a[i].y * w[1].w + a[i].z * w[2].w + a[i].w * w[3].w;
        }
    }

    const float4 ba = *(const float4*)(b10 + tx * 4);
    #pragma unroll
    for (int i = 0; i < 4; ++i) {
        float4 t;
        t.x = fmaxf(acc[i][0] + ba.x, 0.f);
        t.y = fmaxf(acc[i][1] + ba.y, 0.f);
        t.z = fmaxf(acc[i][2] + ba.z, 0.f);
        t.w = fmaxf(acc[i][3] + ba.w, 0.f);
        *(float4*)&Ts[ty * 4 + i][tx * 4] = t;
    }
    __syncthreads();

    #pragma unroll
    for (int i = 0; i < 4; ++i)
        #pragma unroll
        for (int j = 0; j < 4; ++j) acc[i][j] = 0.f;

    #pragma unroll
    for (int k0 = 0; k0 < 64; k0 += 4) {
        float4 a[4], w[4];
        #pragma unroll
        for (int i = 0; i < 4; ++i) a[i] = *(const float4*)&Ts[ty * 4 + i][k0];
        #pragma unroll
        for (int j = 0; j < 4; ++j) w[j] = *(const float4*)&Wbs[k0 + j][tx * 4];
        #pragma unroll
        for (int i = 0; i < 4; ++i) {
            acc[i][0] += a[i].x * w[0].x + a[i].y * w[1].x + a[i].z * w[2].x + a[i].w * w[3].x;
            acc[i][1] += a[i].x * w[0].y + a[i].y * w[1].y + a[i].z * w[2].y + a[i].w * w[3].y;
            acc[i][2] += a[i].x * w[0].z + a[i].y * w[1].z + a[i].z * w[2].z + a[i].w * w[3].z;
            acc[i][3] += a[i].x * w[0].w + a[i].y * w[1].w + a[i].z * w[2].w + a[i].w * w[3].w;
        }
    }

    const float4 bb = *(const float4*)(b11 + tx * 4);
    #pragma unroll
    for (int i = 0; i < 4; ++i) {
        float4 o;
        o.x = acc[i][0] + bb.x;
        o.y = acc[i][1] + bb.y;
        o.z = acc[i][2] + bb.z;
        o.w = acc[i][3] + bb.w;
        *(float4*)(out + (r0 + (size_t)(ty * 4 + i)) * 64 + tx * 4) = o;
    }
}

// ---------------------------------------------------------------------------
extern "C" void kernel_launch(void* const* d_in, const int* in_sizes, int n_in,
                              void* d_out, int out_size, void* d_ws, size_t ws_size,
                              hipStream_t stream)
{
    const float* X   = (const float*)d_in[0];
    const float* STE = (const float*)d_in[1];
    const float* W7  = (const float*)d_in[2];
    const float* b7  = (const float*)d_in[3];
    const float* W8  = (const float*)d_in[4];
    const float* b8  = (const float*)d_in[5];
    const float* W9  = (const float*)d_in[6];
    const float* b9  = (const float*)d_in[7];
    const float* W10 = (const float*)d_in[8];
    const float* b10 = (const float*)d_in[9];
    const float* W11 = (const float*)d_in[10];
    const float* b11 = (const float*)d_in[11];

    float* ws  = (float*)d_ws;   // Q | K | V | O
    float* out = (float*)d_out;

    qkv_kernel<<<dim3(RTOT / 128, 3), 256, 0, stream>>>(X, STE, W7, b7, W8, b8, W9, b9, ws);
    attn_kernel<<<dim3(BT * 8), 256, 0, stream>>>(ws, ws + OOFF);
    proj_kernel<<<dim3(RTOT / 64), 256, 0, stream>>>(ws + OOFF, W10, b10, W11, b11, out);
}

// Round 5
// 213.446 us; speedup vs baseline: 1.8338x; 1.1135x over previous
//
#include <hip/hip_runtime.h>
#include <math.h>

// Problem constants
#define BT    96          // B*T = 8*12
#define NSEQ  512         // N
#define DMODEL 64         // D = K*d
#define RTOT  (BT * NSEQ) // 49152 rows

// Workspace layout (floats)
#define QOFF  0
#define KOFF  ((size_t)RTOT * DMODEL)
#define VOFF  ((size_t)2 * RTOT * DMODEL)
#define OOFF  ((size_t)3 * RTOT * DMODEL)
#define WOFF  ((size_t)4 * RTOT * DMODEL)   // W-fragment cache (96 KB)

#if __has_builtin(__builtin_amdgcn_exp2f)
#define EXP2F(x) __builtin_amdgcn_exp2f(x)
#else
#define EXP2F(x) exp2f(x)
#endif

typedef __attribute__((ext_vector_type(8)))  short short8;
typedef __attribute__((ext_vector_type(16))) float float16v;

static __device__ inline short8 as_s8(uint4 u) {
    union { uint4 u; short8 s; } x; x.u = u; return x.s;
}

// Split 8 fp32 into packed bf16 hi (mantissa-truncate) and bf16 lo
// (residual x-hi is exact in fp32 for any sign, then truncated).
// Pair (2t,2t+1) -> dword: lo16 = elem 2t.
static __device__ inline void split_pack8(const float* v, uint4* hi, uint4* lo) {
    uint32_t h[4], l[4];
    #pragma unroll
    for (int t = 0; t < 4; ++t) {
        float x0 = v[2 * t], x1 = v[2 * t + 1];
        uint32_t u0 = __float_as_uint(x0), u1 = __float_as_uint(x1);
        uint32_t h0 = u0 & 0xffff0000u, h1 = u1 & 0xffff0000u;
        h[t] = h1 | (u0 >> 16);
        float l0 = x0 - __uint_as_float(h0);   // exact
        float l1 = x1 - __uint_as_float(h1);   // exact
        l[t] = (__float_as_uint(l1) & 0xffff0000u) | (__float_as_uint(l0) >> 16);
    }
    *hi = make_uint4(h[0], h[1], h[2], h[3]);
    *lo = make_uint4(l[0], l[1], l[2], l[3]);
}

// ---------------------------------------------------------------------------
// Kernel 0 (R5): pre-split W7/8/9 into bf16 hi/lo B-fragment layout.
// Entry e = w*1024 + c*128 + hh*64 + t*32 + n  (3072 entries each for hi/lo):
//   packs W[c*16+hh*8+j][t*32+n], j=0..7 into one uint4.
// ---------------------------------------------------------------------------
__global__ __launch_bounds__(256) void wprep_kernel(
    const float* __restrict__ W7, const float* __restrict__ W8,
    const float* __restrict__ W9,
    uint4* __restrict__ WfH, uint4* __restrict__ WfL)
{
    const int e = blockIdx.x * 256 + threadIdx.x;   // 0..3071
    const int n  = e & 31;
    const int t  = (e >> 5) & 1;
    const int hh = (e >> 6) & 1;
    const int c  = (e >> 7) & 7;
    const int w  = e >> 10;
    const float* W = (w == 0) ? W7 : (w == 1) ? W8 : W9;
    const int col = t * 32 + n;
    const int k0  = c * 16 + hh * 8;
    float v[8];
    #pragma unroll
    for (int j = 0; j < 8; ++j) v[j] = W[(size_t)(k0 + j) * 64 + col];
    uint4 hi, lo;
    split_pack8(v, &hi, &lo);
    WfH[e] = hi;
    WfL[e] = lo;
}

// ---------------------------------------------------------------------------
// Kernel 1 (R5): MFMA QKV. 1 wave/block, 32 rows x (3 mats x 64 cols).
// A-frags (H rows, split bf16) loaded per-lane from X/STE: lane l reads
// H[base + (l&31)][c*16 + (l>>5)*8 .. +7]. B-frags from the wprep cache
// (coalesced, L2-hot). acc += Ahi*Bhi + Alo*Bhi + Ahi*Blo  (lo*lo dropped).
// Zero LDS.
// ---------------------------------------------------------------------------
__global__ __launch_bounds__(64) void qkv_kernel(
    const float* __restrict__ X, const float* __restrict__ STE,
    const uint4* __restrict__ WfH, const uint4* __restrict__ WfL,
    const float* __restrict__ b7, const float* __restrict__ b8,
    const float* __restrict__ b9,
    float* __restrict__ qkv)
{
    const int lane = threadIdx.x;
    const int l31  = lane & 31;
    const int hh   = lane >> 5;
    const size_t row = (size_t)blockIdx.x * 32 + l31;

    float16v acc[3][2];
    #pragma unroll
    for (int w = 0; w < 3; ++w)
        #pragma unroll
        for (int t = 0; t < 2; ++t)
            #pragma unroll
            for (int i = 0; i < 16; ++i) acc[w][t][i] = 0.f;

    #pragma unroll 4
    for (int c = 0; c < 8; ++c) {
        const float* src = (c < 4) ? X : STE;
        const int off = (c & 3) * 16 + hh * 8;
        const float* ap = src + row * 64 + off;
        float av[8];
        {
            float4 a0 = *(const float4*)(ap);
            float4 a1 = *(const float4*)(ap + 4);
            av[0] = a0.x; av[1] = a0.y; av[2] = a0.z; av[3] = a0.w;
            av[4] = a1.x; av[5] = a1.y; av[6] = a1.z; av[7] = a1.w;
        }
        uint4 ahi, alo;
        split_pack8(av, &ahi, &alo);

        #pragma unroll
        for (int w = 0; w < 3; ++w) {
            #pragma unroll
            for (int t = 0; t < 2; ++t) {
                const int ei = w * 1024 + c * 128 + hh * 64 + t * 32 + l31;
                const uint4 bh = WfH[ei];
                const uint4 bl = WfL[ei];
                acc[w][t] = __builtin_amdgcn_mfma_f32_32x32x16_bf16(
                    as_s8(ahi), as_s8(bh), acc[w][t], 0, 0, 0);
                acc[w][t] = __builtin_amdgcn_mfma_f32_32x32x16_bf16(
                    as_s8(alo), as_s8(bh), acc[w][t], 0, 0, 0);
                acc[w][t] = __builtin_amdgcn_mfma_f32_32x32x16_bf16(
                    as_s8(ahi), as_s8(bl), acc[w][t], 0, 0, 0);
            }
        }
    }

    // Epilogue: bias + relu + store. C-frag: col = t*32+l31 (output col),
    // reg r -> row (r&3) + 8*(r>>2) + 4*hh within the 32-row tile.
    const size_t blockrow = (size_t)blockIdx.x * 32;
    #pragma unroll
    for (int w = 0; w < 3; ++w) {
        const float* bv = (w == 0) ? b7 : (w == 1) ? b8 : b9;
        float* obase = qkv + (size_t)w * ((size_t)RTOT * DMODEL);
        #pragma unroll
        for (int t = 0; t < 2; ++t) {
            const int col = t * 32 + l31;
            const float bias = bv[col];
            #pragma unroll
            for (int r = 0; r < 16; ++r) {
                const int rowC = (r & 3) + 8 * (r >> 2) + 4 * hh;
                obase[(blockrow + rowC) * 64 + col] =
                    fmaxf(acc[w][t][r] + bias, 0.f);
            }
        }
    }
}

// ---------------------------------------------------------------------------
// Kernel 2 (R4, unchanged): MFMA attention, one block per (bt, head).
// ---------------------------------------------------------------------------
__global__ __launch_bounds__(256) void attn_kernel(
    const float* __restrict__ qkv, float* __restrict__ obuf)
{
    __shared__ uint4 ak1[16 * 32];
    __shared__ uint4 ak2[16 * 32];
    __shared__ uint4 vfh[32 * 2 * 9];
    __shared__ uint4 vfl[32 * 2 * 9];
    __shared__ uint4 zslab;

    const int tid  = threadIdx.x;
    const int lane = tid & 63;
    const int l31  = lane & 31;
    const int hh   = lane >> 5;
    const int wv   = tid >> 6;
    const int head = blockIdx.x & 7;
    const int bt   = blockIdx.x >> 3;

    const size_t rowbase = (size_t)bt * NSEQ * 64 + (size_t)head * 8;
    const float* Qp = qkv + QOFF + rowbase;
    const float* Kp = qkv + KOFF + rowbase;
    const float* Vp = qkv + VOFF + rowbase;

    if (tid == 0) zslab = make_uint4(0, 0, 0, 0);

    for (int k = tid; k < NSEQ; k += 256) {
        const float* kr = Kp + (size_t)k * 64;
        float kv[8];
        float4 a = *(const float4*)(kr);
        float4 b = *(const float4*)(kr + 4);
        kv[0] = a.x; kv[1] = a.y; kv[2] = a.z; kv[3] = a.w;
        kv[4] = b.x; kv[5] = b.y; kv[6] = b.z; kv[7] = b.w;
        uint4 hi, lo;
        split_pack8(kv, &hi, &lo);
        ak1[k] = hi;
        ak2[k] = lo;
    }

    for (int e = tid; e < 32 * 2 * 9; e += 256) {
        int s  = e / 18;
        int r  = e % 18;
        int hv = r / 9;
        int n  = r % 9;
        float vv[8];
        #pragma unroll
        for (int j = 0; j < 8; ++j) {
            int key = 16 * s + ((j < 4) ? (4 * hv + j) : (8 + 4 * hv + (j - 4)));
            vv[j] = (n < 8) ? Vp[(size_t)key * 64 + n] : 1.0f;
        }
        uint4 hi, lo;
        split_pack8(vv, &hi, &lo);
        vfh[e] = hi;
        vfl[e] = lo;
    }

    __syncthreads();

    const float C = 0.51012091684045906f;

    for (int qt = wv; qt < 16; qt += 4) {
        const float* qp = Qp + (size_t)(qt * 32 + l31) * 64;
        float qv[8];
        {
            float4 a = *(const float4*)(qp);
            float4 b = *(const float4*)(qp + 4);
            qv[0] = a.x * C; qv[1] = a.y * C; qv[2] = a.z * C; qv[3] = a.w * C;
            qv[4] = b.x * C; qv[5] = b.y * C; qv[6] = b.z * C; qv[7] = b.w * C;
        }
        uint4 qhi, qlo;
        split_pack8(qv, &qhi, &qlo);
        const uint4 bq1 = hh ? qlo : qhi;
        const uint4 bq2 = qhi;

        float16v O;
        #pragma unroll
        for (int i = 0; i < 16; ++i) O[i] = 0.f;

        for (int c = 0; c < 16; ++c) {
            const uint4 a1 = ak1[c * 32 + l31];
            const uint4 a2 = hh ? zslab : ak2[c * 32 + l31];
            const int s0 = 2 * c, s1 = 2 * c + 1;
            const int vi0 = (s0 * 2 + hh) * 9;
            const int vi1 = (s1 * 2 + hh) * 9;
            const bool act = (l31 < 9);
            const uint4 bh0 = act ? vfh[vi0 + l31] : zslab;
            const uint4 bl0 = act ? vfl[vi0 + l31] : zslab;
            const uint4 bh1 = act ? vfh[vi1 + l31] : zslab;
            const uint4 bl1 = act ? vfl[vi1 + l31] : zslab;

            float16v S;
            #pragma unroll
            for (int i = 0; i < 16; ++i) S[i] = 0.f;
            S = __builtin_amdgcn_mfma_f32_32x32x16_bf16(as_s8(a1), as_s8(bq1), S, 0, 0, 0);
            S = __builtin_amdgcn_mfma_f32_32x32x16_bf16(as_s8(a2), as_s8(bq2), S, 0, 0, 0);

            float pv[16];
            #pragma unroll
            for (int i = 0; i < 16; ++i) pv[i] = EXP2F(S[i]);

            uint4 ph0, pl0, ph1, pl1;
            split_pack8(&pv[0], &ph0, &pl0);
            split_pack8(&pv[8], &ph1, &pl1);

            O = __builtin_amdgcn_mfma_f32_32x32x16_bf16(as_s8(ph0), as_s8(bh0), O, 0, 0, 0);
            O = __builtin_amdgcn_mfma_f32_32x32x16_bf16(as_s8(pl0), as_s8(bh0), O, 0, 0, 0);
            O = __builtin_amdgcn_mfma_f32_32x32x16_bf16(as_s8(ph0), as_s8(bl0), O, 0, 0, 0);
            O = __builtin_amdgcn_mfma_f32_32x32x16_bf16(as_s8(ph1), as_s8(bh1), O, 0, 0, 0);
            O = __builtin_amdgcn_mfma_f32_32x32x16_bf16(as_s8(pl1), as_s8(bh1), O, 0, 0, 0);
            O = __builtin_amdgcn_mfma_f32_32x32x16_bf16(as_s8(ph1), as_s8(bl1), O, 0, 0, 0);
        }

        #pragma unroll
        for (int r = 0; r < 16; ++r) {
            float den = __uint_as_float(
                __builtin_amdgcn_ds_swizzle(__float_as_uint(O[r]), 0x100));
            float o = O[r] / den;
            if (l31 < 8) {
                int row = (r & 3) + 8 * (r >> 2) + 4 * hh;
                obuf[rowbase + (size_t)(qt * 32 + row) * 64 + l31] = o;
            }
        }
    }
}

// ---------------------------------------------------------------------------
// Kernel 3: out = relu(O @ W10 + b10) @ W11 + b11   (unchanged)
// ---------------------------------------------------------------------------
__global__ __launch_bounds__(256) void proj_kernel(
    const float* __restrict__ obuf,
    const float* __restrict__ W10, const float* __restrict__ b10,
    const float* __restrict__ W11, const float* __restrict__ b11,
    float* __restrict__ out)
{
    __shared__ float Os[64][68];
    __shared__ float Ts[64][68];
    __shared__ float Was[64][68];
    __shared__ float Wbs[64][68];

    const int tid = threadIdx.x;
    const int tx  = tid & 15;
    const int ty  = tid >> 4;
    const size_t r0 = (size_t)blockIdx.x * 64;

    #pragma unroll
    for (int j = 0; j < 4; ++j) {
        int idx = tid + 256 * j;
        int r   = idx >> 4;
        int cq  = (idx & 15) * 4;
        *(float4*)&Os[r][cq]  = *(const float4*)(obuf + (r0 + (size_t)r) * 64 + cq);
        *(float4*)&Was[r][cq] = *(const float4*)(W10 + (size_t)r * 64 + cq);
        *(float4*)&Wbs[r][cq] = *(const float4*)(W11 + (size_t)r * 64 + cq);
    }
    __syncthreads();

    float acc[4][4];
    #pragma unroll
    for (int i = 0; i < 4; ++i)
        #pragma unroll
        for (int j = 0; j < 4; ++j) acc[i][j] = 0.f;

    #pragma unroll
    for (int k0 = 0; k0 < 64; k0 += 4) {
        float4 a[4], w[4];
        #pragma unroll
        for (int i = 0; i < 4; ++i) a[i] = *(const float4*)&Os[ty * 4 + i][k0];
        #pragma unroll
        for (int j = 0; j < 4; ++j) w[j] = *(const float4*)&Was[k0 + j][tx * 4];
        #pragma unroll
        for (int i = 0; i < 4; ++i) {
            acc[i][0] += a[i].x * w[0].x + a[i].y * w[1].x + a[i].z * w[2].x + a[i].w * w[3].x;
            acc[i][1] += a[i].x * w[0].y + a[i].y * w[1].y + a[i].z * w[2].y + a[i].w * w[3].y;
            acc[i][2] += a[i].x * w[0].z + a[i].y * w[1].z + a[i].z * w[2].z + a[i].w * w[3].z;
            acc[i][3] += a[i].x * w[0].w + a[i].y * w[1].w + a[i].z * w[2].w + a[i].w * w[3].w;
        }
    }

    const float4 ba = *(const float4*)(b10 + tx * 4);
    #pragma unroll
    for (int i = 0; i < 4; ++i) {
        float4 t;
        t.x = fmaxf(acc[i][0] + ba.x, 0.f);
        t.y = fmaxf(acc[i][1] + ba.y, 0.f);
        t.z = fmaxf(acc[i][2] + ba.z, 0.f);
        t.w = fmaxf(acc[i][3] + ba.w, 0.f);
        *(float4*)&Ts[ty * 4 + i][tx * 4] = t;
    }
    __syncthreads();

    #pragma unroll
    for (int i = 0; i < 4; ++i)
        #pragma unroll
        for (int j = 0; j < 4; ++j) acc[i][j] = 0.f;

    #pragma unroll
    for (int k0 = 0; k0 < 64; k0 += 4) {
        float4 a[4], w[4];
        #pragma unroll
        for (int i = 0; i < 4; ++i) a[i] = *(const float4*)&Ts[ty * 4 + i][k0];
        #pragma unroll
        for (int j = 0; j < 4; ++j) w[j] = *(const float4*)&Wbs[k0 + j][tx * 4];
        #pragma unroll
        for (int i = 0; i < 4; ++i) {
            acc[i][0] += a[i].x * w[0].x + a[i].y * w[1].x + a[i].z * w[2].x + a[i].w * w[3].x;
            acc[i][1] += a[i].x * w[0].y + a[i].y * w[1].y + a[i].z * w[2].y + a[i].w * w[3].y;
            acc[i][2] += a[i].x * w[0].z + a[i].y * w[1].z + a[i].z * w[2].z + a[i].w * w[3].z;
            acc[i][3] += a[i].x * w[0].w + a[i].y * w[1].w + a[i].z * w[2].w + a[i].w * w[3].w;
        }
    }

    const float4 bb = *(const float4*)(b11 + tx * 4);
    #pragma unroll
    for (int i = 0; i < 4; ++i) {
        float4 o;
        o.x = acc[i][0] + bb.x;
        o.y = acc[i][1] + bb.y;
        o.z = acc[i][2] + bb.z;
        o.w = acc[i][3] + bb.w;
        *(float4*)(out + (r0 + (size_t)(ty * 4 + i)) * 64 + tx * 4) = o;
    }
}

// ---------------------------------------------------------------------------
extern "C" void kernel_launch(void* const* d_in, const int* in_sizes, int n_in,
                              void* d_out, int out_size, void* d_ws, size_t ws_size,
                              hipStream_t stream)
{
    const float* X   = (const float*)d_in[0];
    const float* STE = (const float*)d_in[1];
    const float* W7  = (const float*)d_in[2];
    const float* b7  = (const float*)d_in[3];
    const float* W8  = (const float*)d_in[4];
    const float* b8  = (const float*)d_in[5];
    const float* W9  = (const float*)d_in[6];
    const float* b9  = (const float*)d_in[7];
    const float* W10 = (const float*)d_in[8];
    const float* b10 = (const float*)d_in[9];
    const float* W11 = (const float*)d_in[10];
    const float* b11 = (const float*)d_in[11];

    float* ws  = (float*)d_ws;   // Q | K | V | O | Wf
    float* out = (float*)d_out;

    uint4* WfH = (uint4*)(ws + WOFF);
    uint4* WfL = WfH + 3072;

    wprep_kernel<<<dim3(12), 256, 0, stream>>>(W7, W8, W9, WfH, WfL);
    qkv_kernel<<<dim3(RTOT / 32), 64, 0, stream>>>(X, STE, WfH, WfL, b7, b8, b9, ws);
    attn_kernel<<<dim3(BT * 8), 256, 0, stream>>>(ws, ws + OOFF);
    proj_kernel<<<dim3(RTOT / 64), 256, 0, stream>>>(ws + OOFF, W10, b10, W11, b11, out);
}